// Round 4
// baseline (433.317 us; speedup 1.0000x reference)
//
#include <hip/hip_runtime.h>
#include <math.h>

#define NFEAT 128
#define NHID 256

typedef __attribute__((ext_vector_type(8))) short short8;
typedef __attribute__((ext_vector_type(4))) float f32x4;

__device__ inline unsigned short f2bf(float f) {
  unsigned u = __float_as_uint(f);
  u += 0x7fffu + ((u >> 16) & 1u);
  return (unsigned short)(u >> 16);
}
__device__ inline float bflo(unsigned u) { return __uint_as_float(u << 16); }
__device__ inline float bfhi(unsigned u) { return __uint_as_float(u & 0xffff0000u); }

// ============ CSR build, bucketed (bucket = dest >> 6; needs N <= 65536) ====

// ---- phase 1: per-bucket edge histogram (LDS-aggregated) ----
__global__ __launch_bounds__(256) void k_hist(const int* __restrict__ col,
                                              int* __restrict__ bcnt, int nE,
                                              int nb) {
  __shared__ int h[1024];
  for (int i = threadIdx.x; i < nb; i += 256) h[i] = 0;
  __syncthreads();
  for (int e = blockIdx.x * 256 + threadIdx.x; e < nE; e += gridDim.x * 256)
    atomicAdd(&h[col[e] >> 6], 1);
  __syncthreads();
  for (int i = threadIdx.x; i < nb; i += 256)
    if (h[i]) atomicAdd(&bcnt[i], h[i]);
}

// ---- phase 2: scan bucket counts (nb <= 1024) ----
__global__ __launch_bounds__(1024) void k_bscan2(const int* __restrict__ bcnt,
                                                 int* __restrict__ bbase,
                                                 int* __restrict__ bcur,
                                                 int* __restrict__ offs, int nb,
                                                 int n) {
  __shared__ int sh[1024];
  int t = threadIdx.x;
  int v = (t < nb) ? bcnt[t] : 0;
  sh[t] = v;
  __syncthreads();
  for (int o = 1; o < 1024; o <<= 1) {
    int u = (t >= o) ? sh[t - o] : 0;
    __syncthreads();
    sh[t] += u;
    __syncthreads();
  }
  if (t < nb) {
    int b = sh[t] - v;
    bbase[t] = b;
    bcur[t] = b;
  }
  if (t == nb - 1) {
    bbase[nb] = sh[t];
    offs[n] = sh[t];  // = E
  }
}

// ---- phase 3: scatter edges into bucket windows (L2-local writes) ----
__global__ __launch_bounds__(256) void k_scatter(const int* __restrict__ row,
                                                 const int* __restrict__ col,
                                                 int* __restrict__ bcur,
                                                 unsigned* __restrict__ tmp,
                                                 int nE) {
  int e = blockIdx.x * 256 + threadIdx.x;
  if (e >= nE) return;
  int c = col[e];
  int pos = atomicAdd(&bcur[c >> 6], 1);
  tmp[pos] = ((unsigned)(c & 63) << 16) | (unsigned)row[e];
}

// ---- phase 4: per-bucket counting sort -> ebuf + offs + dinv ----
__global__ __launch_bounds__(256) void k_bsort(const unsigned* __restrict__ tmp,
                                               const int* __restrict__ bbase,
                                               int* __restrict__ ebuf,
                                               int* __restrict__ offs,
                                               float* __restrict__ dinv, int n) {
  __shared__ int bins[64], cur[64];
  int b = blockIdx.x;
  int beg = bbase[b], end = bbase[b + 1];
  int t = threadIdx.x;
  if (t < 64) bins[t] = 0;
  __syncthreads();
  for (int i = beg + t; i < end; i += 256) atomicAdd(&bins[tmp[i] >> 16], 1);
  __syncthreads();
  if (t < 64) {  // wave 0: exclusive scan of 64 bins via shfl
    int v = bins[t];
    int s = v;
#pragma unroll
    for (int o = 1; o < 64; o <<= 1) {
      int u = __shfl_up(s, o);
      if (t >= o) s += u;
    }
    int off = beg + s - v;
    cur[t] = off;
    int node = b * 64 + t;
    if (node < n) {
      offs[node] = off;
      dinv[node] = rsqrtf((float)(v + 1));  // +1 self loop
    }
  }
  __syncthreads();
  for (int i = beg + t; i < end; i += 256) {
    unsigned p = tmp[i];
    int pos = atomicAdd(&cur[p >> 16], 1);
    ebuf[pos] = (int)(p & 0xffffu);
  }
}

// ---------------- pack both W matrices into bf16 B-fragments ----------------
// frag(nt, ks): lane l holds B[k = ks*32 + (l>>4)*8 + j][n = nt*16 + (l&15)]
__device__ inline void packOne(const float* __restrict__ W,
                               unsigned short* __restrict__ Wp, int idx, int KS,
                               int OUT) {
  int lane = idx & 63;
  int t = idx >> 6;
  int ks = t % KS;
  int nt = t / KS;
  int n = nt * 16 + (lane & 15);
  int k0 = ks * 32 + (lane >> 4) * 8;
  unsigned short v[8];
#pragma unroll
  for (int j = 0; j < 8; j++) v[j] = f2bf(W[(size_t)(k0 + j) * OUT + n]);
  *reinterpret_cast<short8*>(Wp + (size_t)idx * 8) =
      *reinterpret_cast<short8*>(v);
}

__global__ __launch_bounds__(256) void k_packW_both(
    const float* __restrict__ W1, const float* __restrict__ W2,
    unsigned short* __restrict__ W1p, unsigned short* __restrict__ W2p) {
  int idx = blockIdx.x * 256 + threadIdx.x;
  if (idx < 4096) packOne(W1, W1p, idx, 4, 256);
  else packOne(W2, W2p, idx - 4096, 8, 128);
}

// ---------------- xs = bf16(dinv[row] * X) ----------------
__global__ __launch_bounds__(256) void k_cvt(const float* __restrict__ X,
                                             const float* __restrict__ dinv,
                                             unsigned short* __restrict__ xs,
                                             int n) {
  int i4 = blockIdx.x * 256 + threadIdx.x;  // float4 index, 32 per row
  if (i4 >= n * 32) return;
  int row = i4 >> 5;
  float4 v = reinterpret_cast<const float4*>(X)[i4];
  float d = dinv[row];
  unsigned short o[4] = {f2bf(v.x * d), f2bf(v.y * d), f2bf(v.z * d),
                         f2bf(v.w * d)};
  reinterpret_cast<ushort4*>(xs)[i4] = *reinterpret_cast<ushort4*>(o);
}

// ---------------- bf16 gather-aggregate over 128-wide rows ----------------
// OUT[i] = bf16( dinv[i]*(G[i] + sum_{src in-edges} G[src]) + bias )
__global__ __launch_bounds__(256) void k_agg_bf(
    const unsigned int* __restrict__ G, const int* __restrict__ offs,
    const int* __restrict__ ebuf, const float* __restrict__ dinv,
    const float* __restrict__ bias, unsigned int* __restrict__ OUTP, int n) {
  int node = blockIdx.x * 4 + (threadIdx.x >> 6);
  if (node >= n) return;
  int lane = threadIdx.x & 63;
  int beg = offs[node], end = offs[node + 1];
  unsigned su = G[(size_t)node * 64 + lane];
  float a0 = bflo(su), a1 = bfhi(su);
  int e = beg;
  for (; e + 4 <= end; e += 4) {
    int s0 = ebuf[e], s1 = ebuf[e + 1], s2 = ebuf[e + 2], s3 = ebuf[e + 3];
    unsigned v0 = G[(size_t)s0 * 64 + lane];
    unsigned v1 = G[(size_t)s1 * 64 + lane];
    unsigned v2 = G[(size_t)s2 * 64 + lane];
    unsigned v3 = G[(size_t)s3 * 64 + lane];
    a0 += bflo(v0) + bflo(v1) + bflo(v2) + bflo(v3);
    a1 += bfhi(v0) + bfhi(v1) + bfhi(v2) + bfhi(v3);
  }
  for (; e < end; e++) {
    unsigned v = G[(size_t)ebuf[e] * 64 + lane];
    a0 += bflo(v);
    a1 += bfhi(v);
  }
  float d = dinv[node];
  a0 *= d;
  a1 *= d;
  if (bias) {
    a0 += bias[2 * lane];
    a1 += bias[2 * lane + 1];
  }
  OUTP[(size_t)node * 64 + lane] =
      (unsigned)f2bf(a0) | ((unsigned)f2bf(a1) << 16);
}

// ---------------- MFMA GEMM: C[N,OUT] = epi(A[N,K] @ B) ----------------
// MODE 0: epi = relu(x + bias[col]), MODE 1: epi = x * dinv[row]
template <int K, int OUT, int MODE>
__global__ __launch_bounds__(256) void k_mfma(
    const unsigned short* __restrict__ A, const unsigned short* __restrict__ Bp,
    const float* __restrict__ bias, const float* __restrict__ dinv,
    unsigned short* __restrict__ C, int nrt) {
  constexpr int KS = K / 32;
  constexpr int CG = OUT / 64;
  int gw = (blockIdx.x * 256 + threadIdx.x) >> 6;
  int lane = threadIdx.x & 63;
  int rt = gw / CG, cg = gw % CG;
  if (rt >= nrt) return;
  int m0 = rt * 16;
  int mrow = m0 + (lane & 15);
  int quad = lane >> 4;
  f32x4 acc[4] = {};
  const short8* Ap =
      reinterpret_cast<const short8*>(A + (size_t)mrow * K + quad * 8);
#pragma unroll
  for (int ks = 0; ks < KS; ks++) {
    short8 a = Ap[ks * 4];  // advance k by 32 shorts = 4 short8
#pragma unroll
    for (int ct = 0; ct < 4; ct++) {
      int nt = cg * 4 + ct;
      short8 b = *reinterpret_cast<const short8*>(
          Bp + ((size_t)(nt * KS + ks) * 64 + lane) * 8);
      acc[ct] = __builtin_amdgcn_mfma_f32_16x16x32_bf16(a, b, acc[ct], 0, 0, 0);
    }
  }
  int r0 = m0 + quad * 4;
#pragma unroll
  for (int ct = 0; ct < 4; ct++) {
    int c = (cg * 4 + ct) * 16 + (lane & 15);
    float bv = (MODE == 0) ? bias[c] : 0.f;
#pragma unroll
    for (int i = 0; i < 4; i++) {
      float v = acc[ct][i];
      if (MODE == 0) {
        v += bv;
        v = fmaxf(v, 0.f);
      } else {
        v *= dinv[r0 + i];
      }
      C[(size_t)(r0 + i) * OUT + c] = f2bf(v);
    }
  }
}

// ---------------- link head: sigmoid([h[m0];h[m1]] . Wl + bl) ----------------
__global__ __launch_bounds__(256) void k_head(const unsigned int* __restrict__ H,
                                              const int* __restrict__ mask,
                                              const float* __restrict__ Wl,
                                              const float* __restrict__ bl,
                                              float* __restrict__ out, int P) {
  int p = blockIdx.x * 4 + (threadIdx.x >> 6);
  if (p >= P) return;
  int lane = threadIdx.x & 63;
  int m0 = mask[2 * p], m1 = mask[2 * p + 1];
  unsigned u0 = H[(size_t)m0 * 64 + lane];
  unsigned u1 = H[(size_t)m1 * 64 + lane];
  float s = bflo(u0) * Wl[2 * lane] + bfhi(u0) * Wl[2 * lane + 1] +
            bflo(u1) * Wl[128 + 2 * lane] + bfhi(u1) * Wl[129 + 2 * lane];
#pragma unroll
  for (int o = 32; o; o >>= 1) s += __shfl_down(s, o);
  if (lane == 0) out[p] = 1.0f / (1.0f + expf(-(s + bl[0])));
}

extern "C" void kernel_launch(void* const* d_in, const int* in_sizes, int n_in,
                              void* d_out, int out_size, void* d_ws,
                              size_t ws_size, hipStream_t stream) {
  const int* edge = (const int*)d_in[0];
  const float* feat = (const float*)d_in[1];
  const int* mask = (const int*)d_in[2];
  const float* W1 = (const float*)d_in[3];
  const float* b1 = (const float*)d_in[4];
  const float* W2 = (const float*)d_in[5];
  const float* b2 = (const float*)d_in[6];
  const float* Wl = (const float*)d_in[7];
  const float* bl = (const float*)d_in[8];
  float* out = (float*)d_out;

  const int E = in_sizes[0] / 2;
  const int N = in_sizes[1] / NFEAT;  // must be <= 65536 (16-bit row pack)
  const int P = in_sizes[2] / 2;
  const int* rowp = edge;
  const int* colp = edge + E;
  const int nrt = N / 16;             // 3125 for N=50000
  const int nb = (N + 63) / 64;       // 782 buckets (<= 1024 required)

  auto aln = [](size_t x) { return (x + 255) & ~(size_t)255; };
  char* w = (char*)d_ws;
  int* bcnt = (int*)w;             w += aln((size_t)1024 * 4);
  int* bbase = (int*)w;            w += aln((size_t)1025 * 4);
  int* bcur = (int*)w;             w += aln((size_t)1024 * 4);
  int* offs = (int*)w;             w += aln((size_t)(N + 1) * 4);
  int* ebuf = (int*)w;             w += aln((size_t)E * 4);
  unsigned* tmp = (unsigned*)w;    w += aln((size_t)E * 4);
  float* dinv = (float*)w;         w += aln((size_t)N * 4);
  unsigned short* xs = (unsigned short*)w;  w += aln((size_t)N * NFEAT * 2);
  unsigned short* z = (unsigned short*)w;   w += aln((size_t)N * NFEAT * 2);
  unsigned short* h1 = (unsigned short*)w;  w += aln((size_t)N * NHID * 2);
  unsigned short* g2 = (unsigned short*)w;  w += aln((size_t)N * NFEAT * 2);
  unsigned short* hf = (unsigned short*)w;  w += aln((size_t)N * NFEAT * 2);
  unsigned short* W1p = (unsigned short*)w; w += aln((size_t)NFEAT * NHID * 2);
  unsigned short* W2p = (unsigned short*)w; w += aln((size_t)NHID * NFEAT * 2);

  // ---- CSR build (bucketed) ----
  hipMemsetAsync(bcnt, 0, (size_t)nb * 4, stream);
  k_hist<<<128, 256, 0, stream>>>(colp, bcnt, E, nb);
  k_bscan2<<<1, 1024, 0, stream>>>(bcnt, bbase, bcur, offs, nb, N);
  k_scatter<<<(E + 255) / 256, 256, 0, stream>>>(rowp, colp, bcur, tmp, E);
  k_bsort<<<nb, 256, 0, stream>>>(tmp, bbase, ebuf, offs, dinv, N);
  k_packW_both<<<32, 256, 0, stream>>>(W1, W2, W1p, W2p);

  // xs = bf16(dinv * X)
  k_cvt<<<(N * 32 + 255) / 256, 256, 0, stream>>>(feat, dinv, xs, N);
  // z = dinv .* (sum_in xs + xs_self)            [= A_norm @ X, bf16]
  k_agg_bf<<<(N + 3) / 4, 256, 0, stream>>>((const unsigned*)xs, offs, ebuf,
                                            dinv, nullptr, (unsigned*)z, N);
  // h1 = relu(z @ W1 + b1)
  k_mfma<NFEAT, NHID, 0><<<(nrt * (NHID / 64) + 3) / 4, 256, 0, stream>>>(
      z, W1p, b1, nullptr, h1, nrt);
  // g2 = (h1 @ W2) .* dinv[row]
  k_mfma<NHID, NFEAT, 1><<<(nrt * (NFEAT / 64) + 3) / 4, 256, 0, stream>>>(
      h1, W2p, nullptr, dinv, g2, nrt);
  // h = dinv .* (sum_in g2 + g2_self) + b2
  k_agg_bf<<<(N + 3) / 4, 256, 0, stream>>>((const unsigned*)g2, offs, ebuf,
                                            dinv, b2, (unsigned*)hf, N);
  // head
  k_head<<<(P + 3) / 4, 256, 0, stream>>>((const unsigned*)hf, mask, Wl, bl,
                                          out, P);
}

// Round 5
// 298.958 us; speedup vs baseline: 1.4494x; 1.4494x over previous
//
#include <hip/hip_runtime.h>
#include <math.h>

#define NFEAT 128
#define NHID 256
#define NBLK 64  // partition blocks; (block,bucket) segment avg = E/(NBLK*nb) = 16 edges = 64B

typedef __attribute__((ext_vector_type(8))) short short8;
typedef __attribute__((ext_vector_type(4))) float f32x4;

__device__ inline unsigned short f2bf(float f) {
  unsigned u = __float_as_uint(f);
  u += 0x7fffu + ((u >> 16) & 1u);
  return (unsigned short)(u >> 16);
}
__device__ inline float bflo(unsigned u) { return __uint_as_float(u << 16); }
__device__ inline float bfhi(unsigned u) { return __uint_as_float(u & 0xffff0000u); }

// ============ CSR build: deterministic 2-pass partition, no global atomics ==
// bucket = dest >> 6 (64 nodes/bucket); needs N <= 65536 (16-bit packing)

// ---- per-(block,bucket) histogram ----
__global__ __launch_bounds__(256) void k_hist2(const int* __restrict__ col,
                                               int* __restrict__ hist2d, int nE,
                                               int nb) {
  __shared__ int h[1024];
  for (int i = threadIdx.x; i < nb; i += 256) h[i] = 0;
  __syncthreads();
  int chunk = (nE + NBLK - 1) / NBLK;
  int beg = blockIdx.x * chunk, end = min(beg + chunk, nE);
  for (int e = beg + threadIdx.x; e < end; e += 256)
    atomicAdd(&h[col[e] >> 6], 1);
  __syncthreads();
  for (int i = threadIdx.x; i < nb; i += 256)
    hist2d[i * NBLK + blockIdx.x] = h[i];
}

// ---- scan phase 1: per-256-chunk sums ----
__global__ __launch_bounds__(256) void k_bsum(const int* __restrict__ a,
                                              int* __restrict__ psum, int S) {
  int i = blockIdx.x * 256 + threadIdx.x;
  int v = (i < S) ? a[i] : 0;
#pragma unroll
  for (int o = 32; o; o >>= 1) v += __shfl_down(v, o);
  __shared__ int ws[4];
  if ((threadIdx.x & 63) == 0) ws[threadIdx.x >> 6] = v;
  __syncthreads();
  if (threadIdx.x == 0) psum[blockIdx.x] = ws[0] + ws[1] + ws[2] + ws[3];
}

// ---- scan phase 2: scan chunk sums (nc <= 256) ----
__global__ __launch_bounds__(256) void k_s2(const int* __restrict__ psum,
                                            int* __restrict__ pbase, int nc) {
  __shared__ int sh[256];
  int t = threadIdx.x;
  int v = (t < nc) ? psum[t] : 0;
  sh[t] = v;
  __syncthreads();
  for (int o = 1; o < 256; o <<= 1) {
    int u = (t >= o) ? sh[t - o] : 0;
    __syncthreads();
    sh[t] += u;
    __syncthreads();
  }
  if (t < nc) pbase[t] = sh[t] - v;
}

// ---- scan phase 3: element-wise exclusive scan ----
__global__ __launch_bounds__(256) void k_s3(const int* __restrict__ a,
                                            const int* __restrict__ pbase,
                                            int* __restrict__ out, int S) {
  __shared__ int sh[256];
  int t = threadIdx.x;
  int i = blockIdx.x * 256 + t;
  int d = (i < S) ? a[i] : 0;
  sh[t] = d;
  __syncthreads();
  for (int o = 1; o < 256; o <<= 1) {
    int u = (t >= o) ? sh[t - o] : 0;
    __syncthreads();
    sh[t] += u;
    __syncthreads();
  }
  if (i < S) out[i] = pbase[blockIdx.x] + sh[t] - d;
}

// ---- partition: each block writes its own contiguous segments (1 writer/line)
__global__ __launch_bounds__(256) void k_part2(const int* __restrict__ row,
                                               const int* __restrict__ col,
                                               const int* __restrict__ sbase,
                                               unsigned* __restrict__ tmp,
                                               int nE, int nb) {
  __shared__ int cur[1024];
  for (int i = threadIdx.x; i < nb; i += 256)
    cur[i] = sbase[i * NBLK + blockIdx.x];
  __syncthreads();
  int chunk = (nE + NBLK - 1) / NBLK;
  int beg = blockIdx.x * chunk, end = min(beg + chunk, nE);
  for (int e = beg + threadIdx.x; e < end; e += 256) {
    int c = col[e];
    int pos = atomicAdd(&cur[c >> 6], 1);
    tmp[pos] = ((unsigned)(c & 63) << 16) | (unsigned)row[e];
  }
}

// ---- per-bucket counting sort -> ebuf + offs + dinv ----
__global__ __launch_bounds__(256) void k_bsort(const unsigned* __restrict__ tmp,
                                               const int* __restrict__ sbase,
                                               int* __restrict__ ebuf,
                                               int* __restrict__ offs,
                                               float* __restrict__ dinv, int n,
                                               int nE, int nb) {
  __shared__ int bins[64], cur[64];
  int b = blockIdx.x;
  int beg = sbase[b * NBLK];
  int end = (b == nb - 1) ? nE : sbase[(b + 1) * NBLK];
  int t = threadIdx.x;
  if (t == 0 && b == nb - 1) offs[n] = nE;
  if (t < 64) bins[t] = 0;
  __syncthreads();
  for (int i = beg + t; i < end; i += 256) atomicAdd(&bins[tmp[i] >> 16], 1);
  __syncthreads();
  if (t < 64) {  // wave 0: exclusive scan of 64 bins via shfl
    int v = bins[t];
    int s = v;
#pragma unroll
    for (int o = 1; o < 64; o <<= 1) {
      int u = __shfl_up(s, o);
      if (t >= o) s += u;
    }
    int off = beg + s - v;
    cur[t] = off;
    int node = b * 64 + t;
    if (node < n) {
      offs[node] = off;
      dinv[node] = rsqrtf((float)(v + 1));  // +1 self loop
    }
  }
  __syncthreads();
  for (int i = beg + t; i < end; i += 256) {
    unsigned p = tmp[i];
    int pos = atomicAdd(&cur[p >> 16], 1);
    ebuf[pos] = (int)(p & 0xffffu);
  }
}

// ---------------- pack both W matrices into bf16 B-fragments ----------------
// frag(nt, ks): lane l holds B[k = ks*32 + (l>>4)*8 + j][n = nt*16 + (l&15)]
__device__ inline void packOne(const float* __restrict__ W,
                               unsigned short* __restrict__ Wp, int idx, int KS,
                               int OUT) {
  int lane = idx & 63;
  int t = idx >> 6;
  int ks = t % KS;
  int nt = t / KS;
  int n = nt * 16 + (lane & 15);
  int k0 = ks * 32 + (lane >> 4) * 8;
  unsigned short v[8];
#pragma unroll
  for (int j = 0; j < 8; j++) v[j] = f2bf(W[(size_t)(k0 + j) * OUT + n]);
  *reinterpret_cast<short8*>(Wp + (size_t)idx * 8) =
      *reinterpret_cast<short8*>(v);
}

__global__ __launch_bounds__(256) void k_packW_both(
    const float* __restrict__ W1, const float* __restrict__ W2,
    unsigned short* __restrict__ W1p, unsigned short* __restrict__ W2p) {
  int idx = blockIdx.x * 256 + threadIdx.x;
  if (idx < 4096) packOne(W1, W1p, idx, 4, 256);
  else packOne(W2, W2p, idx - 4096, 8, 128);
}

// ---------------- xs = bf16(dinv[row] * X) ----------------
__global__ __launch_bounds__(256) void k_cvt(const float* __restrict__ X,
                                             const float* __restrict__ dinv,
                                             unsigned short* __restrict__ xs,
                                             int n) {
  int i4 = blockIdx.x * 256 + threadIdx.x;  // float4 index, 32 per row
  if (i4 >= n * 32) return;
  int row = i4 >> 5;
  float4 v = reinterpret_cast<const float4*>(X)[i4];
  float d = dinv[row];
  unsigned short o[4] = {f2bf(v.x * d), f2bf(v.y * d), f2bf(v.z * d),
                         f2bf(v.w * d)};
  reinterpret_cast<ushort4*>(xs)[i4] = *reinterpret_cast<ushort4*>(o);
}

// ---------------- bf16 gather-aggregate over 128-wide rows ----------------
// OUT[i] = bf16( dinv[i]*(G[i] + sum_{src in-edges} G[src]) + bias )
__global__ __launch_bounds__(256) void k_agg_bf(
    const unsigned int* __restrict__ G, const int* __restrict__ offs,
    const int* __restrict__ ebuf, const float* __restrict__ dinv,
    const float* __restrict__ bias, unsigned int* __restrict__ OUTP, int n) {
  int node = blockIdx.x * 4 + (threadIdx.x >> 6);
  if (node >= n) return;
  int lane = threadIdx.x & 63;
  int beg = offs[node], end = offs[node + 1];
  unsigned su = G[(size_t)node * 64 + lane];
  float a0 = bflo(su), a1 = bfhi(su);
  int e = beg;
  for (; e + 4 <= end; e += 4) {
    int s0 = ebuf[e], s1 = ebuf[e + 1], s2 = ebuf[e + 2], s3 = ebuf[e + 3];
    unsigned v0 = G[(size_t)s0 * 64 + lane];
    unsigned v1 = G[(size_t)s1 * 64 + lane];
    unsigned v2 = G[(size_t)s2 * 64 + lane];
    unsigned v3 = G[(size_t)s3 * 64 + lane];
    a0 += bflo(v0) + bflo(v1) + bflo(v2) + bflo(v3);
    a1 += bfhi(v0) + bfhi(v1) + bfhi(v2) + bfhi(v3);
  }
  for (; e < end; e++) {
    unsigned v = G[(size_t)ebuf[e] * 64 + lane];
    a0 += bflo(v);
    a1 += bfhi(v);
  }
  float d = dinv[node];
  a0 *= d;
  a1 *= d;
  if (bias) {
    a0 += bias[2 * lane];
    a1 += bias[2 * lane + 1];
  }
  OUTP[(size_t)node * 64 + lane] =
      (unsigned)f2bf(a0) | ((unsigned)f2bf(a1) << 16);
}

// ---------------- MFMA GEMM: C[N,OUT] = epi(A[N,K] @ B) ----------------
// MODE 0: epi = relu(x + bias[col]), MODE 1: epi = x * dinv[row]
template <int K, int OUT, int MODE>
__global__ __launch_bounds__(256) void k_mfma(
    const unsigned short* __restrict__ A, const unsigned short* __restrict__ Bp,
    const float* __restrict__ bias, const float* __restrict__ dinv,
    unsigned short* __restrict__ C, int nrt) {
  constexpr int KS = K / 32;
  constexpr int CG = OUT / 64;
  int gw = (blockIdx.x * 256 + threadIdx.x) >> 6;
  int lane = threadIdx.x & 63;
  int rt = gw / CG, cg = gw % CG;
  if (rt >= nrt) return;
  int m0 = rt * 16;
  int mrow = m0 + (lane & 15);
  int quad = lane >> 4;
  f32x4 acc[4] = {};
  const short8* Ap =
      reinterpret_cast<const short8*>(A + (size_t)mrow * K + quad * 8);
#pragma unroll
  for (int ks = 0; ks < KS; ks++) {
    short8 a = Ap[ks * 4];  // advance k by 32 shorts = 4 short8
#pragma unroll
    for (int ct = 0; ct < 4; ct++) {
      int nt = cg * 4 + ct;
      short8 b = *reinterpret_cast<const short8*>(
          Bp + ((size_t)(nt * KS + ks) * 64 + lane) * 8);
      acc[ct] = __builtin_amdgcn_mfma_f32_16x16x32_bf16(a, b, acc[ct], 0, 0, 0);
    }
  }
  int r0 = m0 + quad * 4;
#pragma unroll
  for (int ct = 0; ct < 4; ct++) {
    int c = (cg * 4 + ct) * 16 + (lane & 15);
    float bv = (MODE == 0) ? bias[c] : 0.f;
#pragma unroll
    for (int i = 0; i < 4; i++) {
      float v = acc[ct][i];
      if (MODE == 0) {
        v += bv;
        v = fmaxf(v, 0.f);
      } else {
        v *= dinv[r0 + i];
      }
      C[(size_t)(r0 + i) * OUT + c] = f2bf(v);
    }
  }
}

// ---------------- link head: sigmoid([h[m0];h[m1]] . Wl + bl) ----------------
__global__ __launch_bounds__(256) void k_head(const unsigned int* __restrict__ H,
                                              const int* __restrict__ mask,
                                              const float* __restrict__ Wl,
                                              const float* __restrict__ bl,
                                              float* __restrict__ out, int P) {
  int p = blockIdx.x * 4 + (threadIdx.x >> 6);
  if (p >= P) return;
  int lane = threadIdx.x & 63;
  int m0 = mask[2 * p], m1 = mask[2 * p + 1];
  unsigned u0 = H[(size_t)m0 * 64 + lane];
  unsigned u1 = H[(size_t)m1 * 64 + lane];
  float s = bflo(u0) * Wl[2 * lane] + bfhi(u0) * Wl[2 * lane + 1] +
            bflo(u1) * Wl[128 + 2 * lane] + bfhi(u1) * Wl[129 + 2 * lane];
#pragma unroll
  for (int o = 32; o; o >>= 1) s += __shfl_down(s, o);
  if (lane == 0) out[p] = 1.0f / (1.0f + expf(-(s + bl[0])));
}

extern "C" void kernel_launch(void* const* d_in, const int* in_sizes, int n_in,
                              void* d_out, int out_size, void* d_ws,
                              size_t ws_size, hipStream_t stream) {
  const int* edge = (const int*)d_in[0];
  const float* feat = (const float*)d_in[1];
  const int* mask = (const int*)d_in[2];
  const float* W1 = (const float*)d_in[3];
  const float* b1 = (const float*)d_in[4];
  const float* W2 = (const float*)d_in[5];
  const float* b2 = (const float*)d_in[6];
  const float* Wl = (const float*)d_in[7];
  const float* bl = (const float*)d_in[8];
  float* out = (float*)d_out;

  const int E = in_sizes[0] / 2;
  const int N = in_sizes[1] / NFEAT;  // must be <= 65536 (16-bit packing)
  const int P = in_sizes[2] / 2;
  const int* rowp = edge;
  const int* colp = edge + E;
  const int nrt = N / 16;             // 3125 for N=50000
  const int nb = (N + 63) / 64;       // 782 buckets (<= 1024 required)
  const int S = nb * NBLK;            // 50048 hist entries
  const int nS = (S + 255) / 256;     // 196 scan chunks (<= 256 required)

  auto aln = [](size_t x) { return (x + 255) & ~(size_t)255; };
  char* w = (char*)d_ws;
  int* hist2d = (int*)w;           w += aln((size_t)S * 4);
  int* sbase = (int*)w;            w += aln((size_t)S * 4);
  int* psum = (int*)w;             w += aln((size_t)256 * 4);
  int* pbase = (int*)w;            w += aln((size_t)256 * 4);
  int* offs = (int*)w;             w += aln((size_t)(N + 1) * 4);
  int* ebuf = (int*)w;             w += aln((size_t)E * 4);
  unsigned* tmp = (unsigned*)w;    w += aln((size_t)E * 4);
  float* dinv = (float*)w;         w += aln((size_t)N * 4);
  unsigned short* xs = (unsigned short*)w;  w += aln((size_t)N * NFEAT * 2);
  unsigned short* z = (unsigned short*)w;   w += aln((size_t)N * NFEAT * 2);
  unsigned short* h1 = (unsigned short*)w;  w += aln((size_t)N * NHID * 2);
  unsigned short* g2 = (unsigned short*)w;  w += aln((size_t)N * NFEAT * 2);
  unsigned short* hf = (unsigned short*)w;  w += aln((size_t)N * NFEAT * 2);
  unsigned short* W1p = (unsigned short*)w; w += aln((size_t)NFEAT * NHID * 2);
  unsigned short* W2p = (unsigned short*)w; w += aln((size_t)NHID * NFEAT * 2);

  // ---- CSR build: deterministic 2-pass partition ----
  k_hist2<<<NBLK, 256, 0, stream>>>(colp, hist2d, E, nb);
  k_bsum<<<nS, 256, 0, stream>>>(hist2d, psum, S);
  k_s2<<<1, 256, 0, stream>>>(psum, pbase, nS);
  k_s3<<<nS, 256, 0, stream>>>(hist2d, pbase, sbase, S);
  k_part2<<<NBLK, 256, 0, stream>>>(rowp, colp, sbase, tmp, E, nb);
  k_bsort<<<nb, 256, 0, stream>>>(tmp, sbase, ebuf, offs, dinv, N, E, nb);
  k_packW_both<<<32, 256, 0, stream>>>(W1, W2, W1p, W2p);

  // xs = bf16(dinv * X)
  k_cvt<<<(N * 32 + 255) / 256, 256, 0, stream>>>(feat, dinv, xs, N);
  // z = dinv .* (sum_in xs + xs_self)            [= A_norm @ X, bf16]
  k_agg_bf<<<(N + 3) / 4, 256, 0, stream>>>((const unsigned*)xs, offs, ebuf,
                                            dinv, nullptr, (unsigned*)z, N);
  // h1 = relu(z @ W1 + b1)
  k_mfma<NFEAT, NHID, 0><<<(nrt * (NHID / 64) + 3) / 4, 256, 0, stream>>>(
      z, W1p, b1, nullptr, h1, nrt);
  // g2 = (h1 @ W2) .* dinv[row]
  k_mfma<NHID, NFEAT, 1><<<(nrt * (NFEAT / 64) + 3) / 4, 256, 0, stream>>>(
      h1, W2p, nullptr, dinv, g2, nrt);
  // h = dinv .* (sum_in g2 + g2_self) + b2
  k_agg_bf<<<(N + 3) / 4, 256, 0, stream>>>((const unsigned*)g2, offs, ebuf,
                                            dinv, b2, (unsigned*)hf, N);
  // head
  k_head<<<(P + 3) / 4, 256, 0, stream>>>((const unsigned*)hf, mask, Wl, bl,
                                          out, P);
}

// Round 6
// 255.009 us; speedup vs baseline: 1.6992x; 1.1723x over previous
//
#include <hip/hip_runtime.h>
#include <math.h>

#define NFEAT 128
#define NHID 256
#define NBLK 128  // partition blocks; (block,bucket) segment avg = 8 edges = 32B

typedef __attribute__((ext_vector_type(8))) short short8;
typedef __attribute__((ext_vector_type(4))) float f32x4;

__device__ inline unsigned short f2bf(float f) {
  unsigned u = __float_as_uint(f);
  u += 0x7fffu + ((u >> 16) & 1u);
  return (unsigned short)(u >> 16);
}
__device__ inline float bflo(unsigned u) { return __uint_as_float(u << 16); }
__device__ inline float bfhi(unsigned u) { return __uint_as_float(u & 0xffff0000u); }

// ============ CSR build: deterministic 2-pass partition, no global atomics ==
// bucket = dest >> 6 (64 nodes/bucket); needs N <= 65536 (16-bit packing)

// ---- per-(block,bucket) histogram ----
__global__ __launch_bounds__(1024) void k_hist2(const int* __restrict__ col,
                                                int* __restrict__ hist2d,
                                                int nE, int nb) {
  __shared__ int h[1024];
  for (int i = threadIdx.x; i < nb; i += 1024) h[i] = 0;
  __syncthreads();
  int chunk = (nE + NBLK - 1) / NBLK;
  int beg = blockIdx.x * chunk, end = min(beg + chunk, nE);
  for (int e = beg + threadIdx.x; e < end; e += 1024)
    atomicAdd(&h[col[e] >> 6], 1);
  __syncthreads();
  for (int i = threadIdx.x; i < nb; i += 1024)
    hist2d[i * NBLK + blockIdx.x] = h[i];
}

// ---- scan phase 1: per-256-chunk sums ----
__global__ __launch_bounds__(256) void k_bsum(const int* __restrict__ a,
                                              int* __restrict__ psum, int S) {
  int i = blockIdx.x * 256 + threadIdx.x;
  int v = (i < S) ? a[i] : 0;
#pragma unroll
  for (int o = 32; o; o >>= 1) v += __shfl_down(v, o);
  __shared__ int ws[4];
  if ((threadIdx.x & 63) == 0) ws[threadIdx.x >> 6] = v;
  __syncthreads();
  if (threadIdx.x == 0) psum[blockIdx.x] = ws[0] + ws[1] + ws[2] + ws[3];
}

// ---- scan phase 2: scan chunk sums (nc <= 1024) ----
__global__ __launch_bounds__(1024) void k_s2(const int* __restrict__ psum,
                                             int* __restrict__ pbase, int nc) {
  __shared__ int sh[1024];
  int t = threadIdx.x;
  int v = (t < nc) ? psum[t] : 0;
  sh[t] = v;
  __syncthreads();
  for (int o = 1; o < 1024; o <<= 1) {
    int u = (t >= o) ? sh[t - o] : 0;
    __syncthreads();
    sh[t] += u;
    __syncthreads();
  }
  if (t < nc) pbase[t] = sh[t] - v;
}

// ---- scan phase 3: element-wise exclusive scan ----
__global__ __launch_bounds__(256) void k_s3(const int* __restrict__ a,
                                            const int* __restrict__ pbase,
                                            int* __restrict__ out, int S) {
  __shared__ int sh[256];
  int t = threadIdx.x;
  int i = blockIdx.x * 256 + t;
  int d = (i < S) ? a[i] : 0;
  sh[t] = d;
  __syncthreads();
  for (int o = 1; o < 256; o <<= 1) {
    int u = (t >= o) ? sh[t - o] : 0;
    __syncthreads();
    sh[t] += u;
    __syncthreads();
  }
  if (i < S) out[i] = pbase[blockIdx.x] + sh[t] - d;
}

// ---- partition: each block writes its own contiguous segments ----
__global__ __launch_bounds__(1024) void k_part2(const int* __restrict__ row,
                                                const int* __restrict__ col,
                                                const int* __restrict__ sbase,
                                                unsigned* __restrict__ tmp,
                                                int nE, int nb) {
  __shared__ int cur[1024];
  for (int i = threadIdx.x; i < nb; i += 1024)
    cur[i] = sbase[i * NBLK + blockIdx.x];
  __syncthreads();
  int chunk = (nE + NBLK - 1) / NBLK;
  int beg = blockIdx.x * chunk, end = min(beg + chunk, nE);
  for (int e = beg + threadIdx.x; e < end; e += 1024) {
    int c = col[e];
    int pos = atomicAdd(&cur[c >> 6], 1);
    tmp[pos] = ((unsigned)(c & 63) << 16) | (unsigned)row[e];
  }
}

// ---- per-bucket counting sort -> ebuf + offs + dinv ----
__global__ __launch_bounds__(256) void k_bsort(const unsigned* __restrict__ tmp,
                                               const int* __restrict__ sbase,
                                               int* __restrict__ ebuf,
                                               int* __restrict__ offs,
                                               float* __restrict__ dinv, int n,
                                               int nE, int nb) {
  __shared__ int bins[64], cur[64];
  int b = blockIdx.x;
  int beg = sbase[b * NBLK];
  int end = (b == nb - 1) ? nE : sbase[(b + 1) * NBLK];
  int t = threadIdx.x;
  if (t == 0 && b == nb - 1) offs[n] = nE;
  if (t < 64) bins[t] = 0;
  __syncthreads();
  for (int i = beg + t; i < end; i += 256) atomicAdd(&bins[tmp[i] >> 16], 1);
  __syncthreads();
  if (t < 64) {  // wave 0: exclusive scan of 64 bins via shfl
    int v = bins[t];
    int s = v;
#pragma unroll
    for (int o = 1; o < 64; o <<= 1) {
      int u = __shfl_up(s, o);
      if (t >= o) s += u;
    }
    int off = beg + s - v;
    cur[t] = off;
    int node = b * 64 + t;
    if (node < n) {
      offs[node] = off;
      dinv[node] = rsqrtf((float)(v + 1));  // +1 self loop
    }
  }
  __syncthreads();
  for (int i = beg + t; i < end; i += 256) {
    unsigned p = tmp[i];
    int pos = atomicAdd(&cur[p >> 16], 1);
    ebuf[pos] = (int)(p & 0xffffu);
  }
}

// ---------------- pack both W matrices into bf16 B-fragments ----------------
// frag(nt, ks): lane l holds B[k = ks*32 + (l>>4)*8 + j][n = nt*16 + (l&15)]
__device__ inline void packOne(const float* __restrict__ W,
                               unsigned short* __restrict__ Wp, int idx, int KS,
                               int OUT) {
  int lane = idx & 63;
  int t = idx >> 6;
  int ks = t % KS;
  int nt = t / KS;
  int n = nt * 16 + (lane & 15);
  int k0 = ks * 32 + (lane >> 4) * 8;
  unsigned short v[8];
#pragma unroll
  for (int j = 0; j < 8; j++) v[j] = f2bf(W[(size_t)(k0 + j) * OUT + n]);
  *reinterpret_cast<short8*>(Wp + (size_t)idx * 8) =
      *reinterpret_cast<short8*>(v);
}

__global__ __launch_bounds__(256) void k_packW_both(
    const float* __restrict__ W1, const float* __restrict__ W2,
    unsigned short* __restrict__ W1p, unsigned short* __restrict__ W2p) {
  int idx = blockIdx.x * 256 + threadIdx.x;
  if (idx < 4096) packOne(W1, W1p, idx, 4, 256);
  else packOne(W2, W2p, idx - 4096, 8, 128);
}

// ---------------- xs = bf16(dinv[row] * X) ----------------
__global__ __launch_bounds__(256) void k_cvt(const float* __restrict__ X,
                                             const float* __restrict__ dinv,
                                             unsigned short* __restrict__ xs,
                                             int n) {
  int i4 = blockIdx.x * 256 + threadIdx.x;  // float4 index, 32 per row
  if (i4 >= n * 32) return;
  int row = i4 >> 5;
  float4 v = reinterpret_cast<const float4*>(X)[i4];
  float d = dinv[row];
  unsigned short o[4] = {f2bf(v.x * d), f2bf(v.y * d), f2bf(v.z * d),
                         f2bf(v.w * d)};
  reinterpret_cast<ushort4*>(xs)[i4] = *reinterpret_cast<ushort4*>(o);
}

// ---------------- bf16 gather-aggregate over 128-wide rows ----------------
// OUT[i] = bf16( dinv[i]*(G[i] + sum_{src in-edges} G[src]) + bias )
__global__ __launch_bounds__(256) void k_agg_bf(
    const unsigned int* __restrict__ G, const int* __restrict__ offs,
    const int* __restrict__ ebuf, const float* __restrict__ dinv,
    const float* __restrict__ bias, unsigned int* __restrict__ OUTP, int n) {
  int node = blockIdx.x * 4 + (threadIdx.x >> 6);
  if (node >= n) return;
  int lane = threadIdx.x & 63;
  int beg = offs[node], end = offs[node + 1];
  unsigned su = G[(size_t)node * 64 + lane];
  float a0 = bflo(su), a1 = bfhi(su);
  int e = beg;
  for (; e + 4 <= end; e += 4) {
    int s0 = ebuf[e], s1 = ebuf[e + 1], s2 = ebuf[e + 2], s3 = ebuf[e + 3];
    unsigned v0 = G[(size_t)s0 * 64 + lane];
    unsigned v1 = G[(size_t)s1 * 64 + lane];
    unsigned v2 = G[(size_t)s2 * 64 + lane];
    unsigned v3 = G[(size_t)s3 * 64 + lane];
    a0 += bflo(v0) + bflo(v1) + bflo(v2) + bflo(v3);
    a1 += bfhi(v0) + bfhi(v1) + bfhi(v2) + bfhi(v3);
  }
  for (; e < end; e++) {
    unsigned v = G[(size_t)ebuf[e] * 64 + lane];
    a0 += bflo(v);
    a1 += bfhi(v);
  }
  float d = dinv[node];
  a0 *= d;
  a1 *= d;
  if (bias) {
    a0 += bias[2 * lane];
    a1 += bias[2 * lane + 1];
  }
  OUTP[(size_t)node * 64 + lane] =
      (unsigned)f2bf(a0) | ((unsigned)f2bf(a1) << 16);
}

// ---------------- MFMA GEMM: C[N,OUT] = epi(A[N,K] @ B) ----------------
// MODE 0: epi = relu(x + bias[col]), MODE 1: epi = x * dinv[row]
template <int K, int OUT, int MODE>
__global__ __launch_bounds__(256) void k_mfma(
    const unsigned short* __restrict__ A, const unsigned short* __restrict__ Bp,
    const float* __restrict__ bias, const float* __restrict__ dinv,
    unsigned short* __restrict__ C, int nrt) {
  constexpr int KS = K / 32;
  constexpr int CG = OUT / 64;
  int gw = (blockIdx.x * 256 + threadIdx.x) >> 6;
  int lane = threadIdx.x & 63;
  int rt = gw / CG, cg = gw % CG;
  if (rt >= nrt) return;
  int m0 = rt * 16;
  int mrow = m0 + (lane & 15);
  int quad = lane >> 4;
  f32x4 acc[4] = {};
  const short8* Ap =
      reinterpret_cast<const short8*>(A + (size_t)mrow * K + quad * 8);
#pragma unroll
  for (int ks = 0; ks < KS; ks++) {
    short8 a = Ap[ks * 4];  // advance k by 32 shorts = 4 short8
#pragma unroll
    for (int ct = 0; ct < 4; ct++) {
      int nt = cg * 4 + ct;
      short8 b = *reinterpret_cast<const short8*>(
          Bp + ((size_t)(nt * KS + ks) * 64 + lane) * 8);
      acc[ct] = __builtin_amdgcn_mfma_f32_16x16x32_bf16(a, b, acc[ct], 0, 0, 0);
    }
  }
  int r0 = m0 + quad * 4;
#pragma unroll
  for (int ct = 0; ct < 4; ct++) {
    int c = (cg * 4 + ct) * 16 + (lane & 15);
    float bv = (MODE == 0) ? bias[c] : 0.f;
#pragma unroll
    for (int i = 0; i < 4; i++) {
      float v = acc[ct][i];
      if (MODE == 0) {
        v += bv;
        v = fmaxf(v, 0.f);
      } else {
        v *= dinv[r0 + i];
      }
      C[(size_t)(r0 + i) * OUT + c] = f2bf(v);
    }
  }
}

// ---------------- link head: sigmoid([h[m0];h[m1]] . Wl + bl) ----------------
__global__ __launch_bounds__(256) void k_head(const unsigned int* __restrict__ H,
                                              const int* __restrict__ mask,
                                              const float* __restrict__ Wl,
                                              const float* __restrict__ bl,
                                              float* __restrict__ out, int P) {
  int p = blockIdx.x * 4 + (threadIdx.x >> 6);
  if (p >= P) return;
  int lane = threadIdx.x & 63;
  int m0 = mask[2 * p], m1 = mask[2 * p + 1];
  unsigned u0 = H[(size_t)m0 * 64 + lane];
  unsigned u1 = H[(size_t)m1 * 64 + lane];
  float s = bflo(u0) * Wl[2 * lane] + bfhi(u0) * Wl[2 * lane + 1] +
            bflo(u1) * Wl[128 + 2 * lane] + bfhi(u1) * Wl[129 + 2 * lane];
#pragma unroll
  for (int o = 32; o; o >>= 1) s += __shfl_down(s, o);
  if (lane == 0) out[p] = 1.0f / (1.0f + expf(-(s + bl[0])));
}

extern "C" void kernel_launch(void* const* d_in, const int* in_sizes, int n_in,
                              void* d_out, int out_size, void* d_ws,
                              size_t ws_size, hipStream_t stream) {
  const int* edge = (const int*)d_in[0];
  const float* feat = (const float*)d_in[1];
  const int* mask = (const int*)d_in[2];
  const float* W1 = (const float*)d_in[3];
  const float* b1 = (const float*)d_in[4];
  const float* W2 = (const float*)d_in[5];
  const float* b2 = (const float*)d_in[6];
  const float* Wl = (const float*)d_in[7];
  const float* bl = (const float*)d_in[8];
  float* out = (float*)d_out;

  const int E = in_sizes[0] / 2;
  const int N = in_sizes[1] / NFEAT;  // must be <= 65536 (16-bit packing)
  const int P = in_sizes[2] / 2;
  const int* rowp = edge;
  const int* colp = edge + E;
  const int nrt = N / 16;             // 3125 for N=50000
  const int nb = (N + 63) / 64;       // 782 buckets (<= 1024 required)
  const int S = nb * NBLK;            // 100096 hist entries
  const int nS = (S + 255) / 256;     // 392 scan chunks (<= 1024 required)

  auto aln = [](size_t x) { return (x + 255) & ~(size_t)255; };
  char* w = (char*)d_ws;
  int* hist2d = (int*)w;           w += aln((size_t)S * 4);
  int* sbase = (int*)w;            w += aln((size_t)S * 4);
  int* psum = (int*)w;             w += aln((size_t)1024 * 4);
  int* pbase = (int*)w;            w += aln((size_t)1024 * 4);
  int* offs = (int*)w;             w += aln((size_t)(N + 1) * 4);
  int* ebuf = (int*)w;             w += aln((size_t)E * 4);
  unsigned* tmp = (unsigned*)w;    w += aln((size_t)E * 4);
  float* dinv = (float*)w;         w += aln((size_t)N * 4);
  unsigned short* xs = (unsigned short*)w;  w += aln((size_t)N * NFEAT * 2);
  unsigned short* z = (unsigned short*)w;   w += aln((size_t)N * NFEAT * 2);
  unsigned short* h1 = (unsigned short*)w;  w += aln((size_t)N * NHID * 2);
  unsigned short* g2 = (unsigned short*)w;  w += aln((size_t)N * NFEAT * 2);
  unsigned short* hf = (unsigned short*)w;  w += aln((size_t)N * NFEAT * 2);
  unsigned short* W1p = (unsigned short*)w; w += aln((size_t)NFEAT * NHID * 2);
  unsigned short* W2p = (unsigned short*)w; w += aln((size_t)NHID * NFEAT * 2);

  // ---- CSR build: deterministic 2-pass partition ----
  k_hist2<<<NBLK, 1024, 0, stream>>>(colp, hist2d, E, nb);
  k_bsum<<<nS, 256, 0, stream>>>(hist2d, psum, S);
  k_s2<<<1, 1024, 0, stream>>>(psum, pbase, nS);
  k_s3<<<nS, 256, 0, stream>>>(hist2d, pbase, sbase, S);
  k_part2<<<NBLK, 1024, 0, stream>>>(rowp, colp, sbase, tmp, E, nb);
  k_bsort<<<nb, 256, 0, stream>>>(tmp, sbase, ebuf, offs, dinv, N, E, nb);
  k_packW_both<<<32, 256, 0, stream>>>(W1, W2, W1p, W2p);

  // xs = bf16(dinv * X)
  k_cvt<<<(N * 32 + 255) / 256, 256, 0, stream>>>(feat, dinv, xs, N);
  // z = dinv .* (sum_in xs + xs_self)            [= A_norm @ X, bf16]
  k_agg_bf<<<(N + 3) / 4, 256, 0, stream>>>((const unsigned*)xs, offs, ebuf,
                                            dinv, nullptr, (unsigned*)z, N);
  // h1 = relu(z @ W1 + b1)
  k_mfma<NFEAT, NHID, 0><<<(nrt * (NHID / 64) + 3) / 4, 256, 0, stream>>>(
      z, W1p, b1, nullptr, h1, nrt);
  // g2 = (h1 @ W2) .* dinv[row]
  k_mfma<NHID, NFEAT, 1><<<(nrt * (NFEAT / 64) + 3) / 4, 256, 0, stream>>>(
      h1, W2p, nullptr, dinv, g2, nrt);
  // h = dinv .* (sum_in g2 + g2_self) + b2
  k_agg_bf<<<(N + 3) / 4, 256, 0, stream>>>((const unsigned*)g2, offs, ebuf,
                                            dinv, b2, (unsigned*)hf, N);
  // head
  k_head<<<(P + 3) / 4, 256, 0, stream>>>((const unsigned*)hf, mask, Wl, bl,
                                          out, P);
}

// Round 7
// 237.069 us; speedup vs baseline: 1.8278x; 1.0757x over previous
//
#include <hip/hip_runtime.h>
#include <math.h>

#define NFEAT 128
#define NHID 256
#define NBLK 128  // partition blocks; (block,bucket) segment avg = 8 edges = 32B

typedef __attribute__((ext_vector_type(8))) short short8;
typedef __attribute__((ext_vector_type(4))) float f32x4;

__device__ inline unsigned short f2bf(float f) {
  unsigned u = __float_as_uint(f);
  u += 0x7fffu + ((u >> 16) & 1u);
  return (unsigned short)(u >> 16);
}
__device__ inline float bflo(unsigned u) { return __uint_as_float(u << 16); }
__device__ inline float bfhi(unsigned u) { return __uint_as_float(u & 0xffff0000u); }

// ============ CSR build: deterministic 2-pass partition, no global atomics ==
// bucket = dest >> 6 (64 nodes/bucket); needs N <= 65536 (16-bit packing)

// ---- per-(block,bucket) histogram ----
__global__ __launch_bounds__(1024) void k_hist2(const int* __restrict__ col,
                                                int* __restrict__ hist2d,
                                                int nE, int nb) {
  __shared__ int h[1024];
  for (int i = threadIdx.x; i < nb; i += 1024) h[i] = 0;
  __syncthreads();
  int chunk = (nE + NBLK - 1) / NBLK;
  int beg = blockIdx.x * chunk, end = min(beg + chunk, nE);
  for (int e = beg + threadIdx.x; e < end; e += 1024)
    atomicAdd(&h[col[e] >> 6], 1);
  __syncthreads();
  for (int i = threadIdx.x; i < nb; i += 1024)
    hist2d[i * NBLK + blockIdx.x] = h[i];
}

// ---- scan phase 1: per-256-chunk sums ----
__global__ __launch_bounds__(256) void k_bsum(const int* __restrict__ a,
                                              int* __restrict__ psum, int S) {
  int i = blockIdx.x * 256 + threadIdx.x;
  int v = (i < S) ? a[i] : 0;
#pragma unroll
  for (int o = 32; o; o >>= 1) v += __shfl_down(v, o);
  __shared__ int ws[4];
  if ((threadIdx.x & 63) == 0) ws[threadIdx.x >> 6] = v;
  __syncthreads();
  if (threadIdx.x == 0) psum[blockIdx.x] = ws[0] + ws[1] + ws[2] + ws[3];
}

// ---- scan phase 2: scan chunk sums (nc <= 1024) ----
__global__ __launch_bounds__(1024) void k_s2(const int* __restrict__ psum,
                                             int* __restrict__ pbase, int nc) {
  __shared__ int sh[1024];
  int t = threadIdx.x;
  int v = (t < nc) ? psum[t] : 0;
  sh[t] = v;
  __syncthreads();
  for (int o = 1; o < 1024; o <<= 1) {
    int u = (t >= o) ? sh[t - o] : 0;
    __syncthreads();
    sh[t] += u;
    __syncthreads();
  }
  if (t < nc) pbase[t] = sh[t] - v;
}

// ---- scan phase 3: element-wise exclusive scan ----
__global__ __launch_bounds__(256) void k_s3(const int* __restrict__ a,
                                            const int* __restrict__ pbase,
                                            int* __restrict__ out, int S) {
  __shared__ int sh[256];
  int t = threadIdx.x;
  int i = blockIdx.x * 256 + t;
  int d = (i < S) ? a[i] : 0;
  sh[t] = d;
  __syncthreads();
  for (int o = 1; o < 256; o <<= 1) {
    int u = (t >= o) ? sh[t - o] : 0;
    __syncthreads();
    sh[t] += u;
    __syncthreads();
  }
  if (i < S) out[i] = pbase[blockIdx.x] + sh[t] - d;
}

// ---- partition: each block writes its own contiguous segments ----
__global__ __launch_bounds__(1024) void k_part2(const int* __restrict__ row,
                                                const int* __restrict__ col,
                                                const int* __restrict__ sbase,
                                                unsigned* __restrict__ tmp,
                                                int nE, int nb) {
  __shared__ int cur[1024];
  for (int i = threadIdx.x; i < nb; i += 1024)
    cur[i] = sbase[i * NBLK + blockIdx.x];
  __syncthreads();
  int chunk = (nE + NBLK - 1) / NBLK;
  int beg = blockIdx.x * chunk, end = min(beg + chunk, nE);
  for (int e = beg + threadIdx.x; e < end; e += 1024) {
    int c = col[e];
    int pos = atomicAdd(&cur[c >> 6], 1);
    tmp[pos] = ((unsigned)(c & 63) << 16) | (unsigned)row[e];
  }
}

// ---- per-bucket counting sort -> ebuf + offs + dinv ----
__global__ __launch_bounds__(256) void k_bsort(const unsigned* __restrict__ tmp,
                                               const int* __restrict__ sbase,
                                               int* __restrict__ ebuf,
                                               int* __restrict__ offs,
                                               float* __restrict__ dinv, int n,
                                               int nE, int nb) {
  __shared__ int bins[64], cur[64];
  int b = blockIdx.x;
  int beg = sbase[b * NBLK];
  int end = (b == nb - 1) ? nE : sbase[(b + 1) * NBLK];
  int t = threadIdx.x;
  if (t == 0 && b == nb - 1) offs[n] = nE;
  if (t < 64) bins[t] = 0;
  __syncthreads();
  for (int i = beg + t; i < end; i += 256) atomicAdd(&bins[tmp[i] >> 16], 1);
  __syncthreads();
  if (t < 64) {  // wave 0: exclusive scan of 64 bins via shfl
    int v = bins[t];
    int s = v;
#pragma unroll
    for (int o = 1; o < 64; o <<= 1) {
      int u = __shfl_up(s, o);
      if (t >= o) s += u;
    }
    int off = beg + s - v;
    cur[t] = off;
    int node = b * 64 + t;
    if (node < n) {
      offs[node] = off;
      dinv[node] = rsqrtf((float)(v + 1));  // +1 self loop
    }
  }
  __syncthreads();
  for (int i = beg + t; i < end; i += 256) {
    unsigned p = tmp[i];
    int pos = atomicAdd(&cur[p >> 16], 1);
    ebuf[pos] = (int)(p & 0xffffu);
  }
}

// ---------------- pack both W matrices into bf16 B-fragments ----------------
// frag(nt, ks): lane l holds B[k = ks*32 + (l>>4)*8 + j][n = nt*16 + (l&15)]
__device__ inline void packOne(const float* __restrict__ W,
                               unsigned short* __restrict__ Wp, int idx, int KS,
                               int OUT) {
  int lane = idx & 63;
  int t = idx >> 6;
  int ks = t % KS;
  int nt = t / KS;
  int n = nt * 16 + (lane & 15);
  int k0 = ks * 32 + (lane >> 4) * 8;
  unsigned short v[8];
#pragma unroll
  for (int j = 0; j < 8; j++) v[j] = f2bf(W[(size_t)(k0 + j) * OUT + n]);
  *reinterpret_cast<short8*>(Wp + (size_t)idx * 8) =
      *reinterpret_cast<short8*>(v);
}

__global__ __launch_bounds__(256) void k_packW_both(
    const float* __restrict__ W1, const float* __restrict__ W2,
    unsigned short* __restrict__ W1p, unsigned short* __restrict__ W2p) {
  int idx = blockIdx.x * 256 + threadIdx.x;
  if (idx < 4096) packOne(W1, W1p, idx, 4, 256);
  else packOne(W2, W2p, idx - 4096, 8, 128);
}

// ---------------- xs = bf16(dinv[row] * X) ----------------
__global__ __launch_bounds__(256) void k_cvt(const float* __restrict__ X,
                                             const float* __restrict__ dinv,
                                             unsigned short* __restrict__ xs,
                                             int n) {
  int i4 = blockIdx.x * 256 + threadIdx.x;  // float4 index, 32 per row
  if (i4 >= n * 32) return;
  int row = i4 >> 5;
  float4 v = reinterpret_cast<const float4*>(X)[i4];
  float d = dinv[row];
  unsigned short o[4] = {f2bf(v.x * d), f2bf(v.y * d), f2bf(v.z * d),
                         f2bf(v.w * d)};
  reinterpret_cast<ushort4*>(xs)[i4] = *reinterpret_cast<ushort4*>(o);
}

// ---------------- bf16 gather-aggregate over 128-wide rows ----------------
// OUT[i] = bf16( dinv[i]*(G[i] + sum_{src in-edges} G[src]) + bias )
__global__ __launch_bounds__(256) void k_agg_bf(
    const unsigned int* __restrict__ G, const int* __restrict__ offs,
    const int* __restrict__ ebuf, const float* __restrict__ dinv,
    const float* __restrict__ bias, unsigned int* __restrict__ OUTP, int n) {
  int node = blockIdx.x * 4 + (threadIdx.x >> 6);
  if (node >= n) return;
  int lane = threadIdx.x & 63;
  int beg = offs[node], end = offs[node + 1];
  unsigned su = G[(size_t)node * 64 + lane];
  float a0 = bflo(su), a1 = bfhi(su);
  int e = beg;
  for (; e + 4 <= end; e += 4) {
    int s0 = ebuf[e], s1 = ebuf[e + 1], s2 = ebuf[e + 2], s3 = ebuf[e + 3];
    unsigned v0 = G[(size_t)s0 * 64 + lane];
    unsigned v1 = G[(size_t)s1 * 64 + lane];
    unsigned v2 = G[(size_t)s2 * 64 + lane];
    unsigned v3 = G[(size_t)s3 * 64 + lane];
    a0 += bflo(v0) + bflo(v1) + bflo(v2) + bflo(v3);
    a1 += bfhi(v0) + bfhi(v1) + bfhi(v2) + bfhi(v3);
  }
  for (; e < end; e++) {
    unsigned v = G[(size_t)ebuf[e] * 64 + lane];
    a0 += bflo(v);
    a1 += bfhi(v);
  }
  float d = dinv[node];
  a0 *= d;
  a1 *= d;
  if (bias) {
    a0 += bias[2 * lane];
    a1 += bias[2 * lane + 1];
  }
  OUTP[(size_t)node * 64 + lane] =
      (unsigned)f2bf(a0) | ((unsigned)f2bf(a1) << 16);
}

// ---------------- fused double GEMM ----------------
// per block (4 waves): 16-row tile.
//   phase A: h1 = relu(z@W1 + b1)  [16x256] -> LDS (row stride 264 shorts)
//   phase B: g2 = (h1@W2) * dinv    [16x128] -> global
__global__ __launch_bounds__(256) void k_mfma_fused(
    const unsigned short* __restrict__ A, const unsigned short* __restrict__ B1p,
    const unsigned short* __restrict__ B2p, const float* __restrict__ b1,
    const float* __restrict__ dinv, unsigned short* __restrict__ G2, int nrt) {
  __shared__ unsigned short sh1[16 * 264];  // +8 pad: 2-way LDS conflicts only
  int rt = blockIdx.x;
  if (rt >= nrt) return;
  int wave = threadIdx.x >> 6;
  int lane = threadIdx.x & 63;
  int m0 = rt * 16;
  int mrow = m0 + (lane & 15);
  int quad = lane >> 4;

  // ---- phase A: cols wave*64 .. wave*64+63 of h1 ----
  f32x4 acc[4] = {};
  const short8* Ap =
      reinterpret_cast<const short8*>(A + (size_t)mrow * NFEAT + quad * 8);
#pragma unroll
  for (int ks = 0; ks < 4; ks++) {
    short8 a = Ap[ks * 4];
#pragma unroll
    for (int ct = 0; ct < 4; ct++) {
      int nt = wave * 4 + ct;
      short8 b = *reinterpret_cast<const short8*>(
          B1p + ((size_t)(nt * 4 + ks) * 64 + lane) * 8);
      acc[ct] = __builtin_amdgcn_mfma_f32_16x16x32_bf16(a, b, acc[ct], 0, 0, 0);
    }
  }
#pragma unroll
  for (int ct = 0; ct < 4; ct++) {
    int c = (wave * 4 + ct) * 16 + (lane & 15);
    float bv = b1[c];
#pragma unroll
    for (int i = 0; i < 4; i++) {
      float v = fmaxf(acc[ct][i] + bv, 0.f);
      sh1[(quad * 4 + i) * 264 + c] = f2bf(v);
    }
  }
  __syncthreads();

  // ---- phase B: cols wave*32 .. wave*32+31 of g2, K=256 from LDS ----
  f32x4 acc2[2] = {};
  const unsigned short* a2 = sh1 + (size_t)(lane & 15) * 264 + quad * 8;
#pragma unroll
  for (int ks = 0; ks < 8; ks++) {
    short8 a = *reinterpret_cast<const short8*>(a2 + ks * 32);
#pragma unroll
    for (int ct = 0; ct < 2; ct++) {
      int nt = wave * 2 + ct;
      short8 b = *reinterpret_cast<const short8*>(
          B2p + ((size_t)(nt * 8 + ks) * 64 + lane) * 8);
      acc2[ct] = __builtin_amdgcn_mfma_f32_16x16x32_bf16(a, b, acc2[ct], 0, 0, 0);
    }
  }
  int r0 = m0 + quad * 4;
  float dv[4];
#pragma unroll
  for (int i = 0; i < 4; i++) dv[i] = dinv[r0 + i];
#pragma unroll
  for (int ct = 0; ct < 2; ct++) {
    int c = (wave * 2 + ct) * 16 + (lane & 15);
#pragma unroll
    for (int i = 0; i < 4; i++)
      G2[(size_t)(r0 + i) * NFEAT + c] = f2bf(acc2[ct][i] * dv[i]);
  }
}

// ---------------- link head: sigmoid([h[m0];h[m1]] . Wl + bl) ----------------
__global__ __launch_bounds__(256) void k_head(const unsigned int* __restrict__ H,
                                              const int* __restrict__ mask,
                                              const float* __restrict__ Wl,
                                              const float* __restrict__ bl,
                                              float* __restrict__ out, int P) {
  int p = blockIdx.x * 4 + (threadIdx.x >> 6);
  if (p >= P) return;
  int lane = threadIdx.x & 63;
  int m0 = mask[2 * p], m1 = mask[2 * p + 1];
  unsigned u0 = H[(size_t)m0 * 64 + lane];
  unsigned u1 = H[(size_t)m1 * 64 + lane];
  float s = bflo(u0) * Wl[2 * lane] + bfhi(u0) * Wl[2 * lane + 1] +
            bflo(u1) * Wl[128 + 2 * lane] + bfhi(u1) * Wl[129 + 2 * lane];
#pragma unroll
  for (int o = 32; o; o >>= 1) s += __shfl_down(s, o);
  if (lane == 0) out[p] = 1.0f / (1.0f + expf(-(s + bl[0])));
}

extern "C" void kernel_launch(void* const* d_in, const int* in_sizes, int n_in,
                              void* d_out, int out_size, void* d_ws,
                              size_t ws_size, hipStream_t stream) {
  const int* edge = (const int*)d_in[0];
  const float* feat = (const float*)d_in[1];
  const int* mask = (const int*)d_in[2];
  const float* W1 = (const float*)d_in[3];
  const float* b1 = (const float*)d_in[4];
  const float* W2 = (const float*)d_in[5];
  const float* b2 = (const float*)d_in[6];
  const float* Wl = (const float*)d_in[7];
  const float* bl = (const float*)d_in[8];
  float* out = (float*)d_out;

  const int E = in_sizes[0] / 2;
  const int N = in_sizes[1] / NFEAT;  // must be <= 65536 (16-bit packing)
  const int P = in_sizes[2] / 2;
  const int* rowp = edge;
  const int* colp = edge + E;
  const int nrt = N / 16;             // 3125 for N=50000
  const int nb = (N + 63) / 64;       // 782 buckets (<= 1024 required)
  const int S = nb * NBLK;            // 100096 hist entries
  const int nS = (S + 255) / 256;     // 392 scan chunks (<= 1024 required)

  auto aln = [](size_t x) { return (x + 255) & ~(size_t)255; };
  char* w = (char*)d_ws;
  int* hist2d = (int*)w;           w += aln((size_t)S * 4);
  int* sbase = (int*)w;            w += aln((size_t)S * 4);
  int* psum = (int*)w;             w += aln((size_t)1024 * 4);
  int* pbase = (int*)w;            w += aln((size_t)1024 * 4);
  int* offs = (int*)w;             w += aln((size_t)(N + 1) * 4);
  int* ebuf = (int*)w;             w += aln((size_t)E * 4);
  unsigned* tmp = (unsigned*)w;    w += aln((size_t)E * 4);
  float* dinv = (float*)w;         w += aln((size_t)N * 4);
  unsigned short* xs = (unsigned short*)w;  w += aln((size_t)N * NFEAT * 2);
  unsigned short* z = (unsigned short*)w;   w += aln((size_t)N * NFEAT * 2);
  unsigned short* g2 = (unsigned short*)w;  w += aln((size_t)N * NFEAT * 2);
  unsigned short* hf = (unsigned short*)w;  w += aln((size_t)N * NFEAT * 2);
  unsigned short* W1p = (unsigned short*)w; w += aln((size_t)NFEAT * NHID * 2);
  unsigned short* W2p = (unsigned short*)w; w += aln((size_t)NHID * NFEAT * 2);

  // ---- CSR build: deterministic 2-pass partition ----
  k_hist2<<<NBLK, 1024, 0, stream>>>(colp, hist2d, E, nb);
  k_bsum<<<nS, 256, 0, stream>>>(hist2d, psum, S);
  k_s2<<<1, 1024, 0, stream>>>(psum, pbase, nS);
  k_s3<<<nS, 256, 0, stream>>>(hist2d, pbase, sbase, S);
  k_part2<<<NBLK, 1024, 0, stream>>>(rowp, colp, sbase, tmp, E, nb);
  k_bsort<<<nb, 256, 0, stream>>>(tmp, sbase, ebuf, offs, dinv, N, E, nb);
  k_packW_both<<<32, 256, 0, stream>>>(W1, W2, W1p, W2p);

  // xs = bf16(dinv * X)
  k_cvt<<<(N * 32 + 255) / 256, 256, 0, stream>>>(feat, dinv, xs, N);
  // z = dinv .* (sum_in xs + xs_self)            [= A_norm @ X, bf16]
  k_agg_bf<<<(N + 3) / 4, 256, 0, stream>>>((const unsigned*)xs, offs, ebuf,
                                            dinv, nullptr, (unsigned*)z, N);
  // g2 = (relu(z@W1+b1) @ W2) .* dinv[row]   (h1 tile stays in LDS)
  k_mfma_fused<<<nrt, 256, 0, stream>>>(z, W1p, W2p, b1, dinv, g2, nrt);
  // h = dinv .* (sum_in g2 + g2_self) + b2
  k_agg_bf<<<(N + 3) / 4, 256, 0, stream>>>((const unsigned*)g2, offs, ebuf,
                                            dinv, b2, (unsigned*)hf, N);
  // head
  k_head<<<(P + 3) / 4, 256, 0, stream>>>((const unsigned*)hf, mask, Wl, bl,
                                          out, P);
}

// Round 8
// 216.907 us; speedup vs baseline: 1.9977x; 1.0930x over previous
//
#include <hip/hip_runtime.h>
#include <math.h>

#define NFEAT 128
#define NHID 256
#define NBLK 128  // partition blocks; (block,bucket) segment avg = 8 edges = 32B

typedef __attribute__((ext_vector_type(8))) short short8;
typedef __attribute__((ext_vector_type(4))) float f32x4;

__device__ inline unsigned short f2bf(float f) {
  unsigned u = __float_as_uint(f);
  u += 0x7fffu + ((u >> 16) & 1u);
  return (unsigned short)(u >> 16);
}
__device__ inline float bflo(unsigned u) { return __uint_as_float(u << 16); }
__device__ inline float bfhi(unsigned u) { return __uint_as_float(u & 0xffff0000u); }

// ============ CSR build: deterministic 2-pass partition, no global atomics ==
// bucket = dest >> 6 (64 nodes/bucket); needs N <= 65536 (16-bit packing)

// ---- per-(block,bucket) histogram ----
__global__ __launch_bounds__(1024) void k_hist2(const int* __restrict__ col,
                                                int* __restrict__ hist2d,
                                                int nE, int nb) {
  __shared__ int h[1024];
  for (int i = threadIdx.x; i < nb; i += 1024) h[i] = 0;
  __syncthreads();
  int chunk = (nE + NBLK - 1) / NBLK;
  int beg = blockIdx.x * chunk, end = min(beg + chunk, nE);
  for (int e = beg + threadIdx.x; e < end; e += 1024)
    atomicAdd(&h[col[e] >> 6], 1);
  __syncthreads();
  for (int i = threadIdx.x; i < nb; i += 1024)
    hist2d[i * NBLK + blockIdx.x] = h[i];
}

// ---- scan phase 1: per-256-chunk sums ----
__global__ __launch_bounds__(256) void k_bsum(const int* __restrict__ a,
                                              int* __restrict__ psum, int S) {
  int i = blockIdx.x * 256 + threadIdx.x;
  int v = (i < S) ? a[i] : 0;
#pragma unroll
  for (int o = 32; o; o >>= 1) v += __shfl_down(v, o);
  __shared__ int ws[4];
  if ((threadIdx.x & 63) == 0) ws[threadIdx.x >> 6] = v;
  __syncthreads();
  if (threadIdx.x == 0) psum[blockIdx.x] = ws[0] + ws[1] + ws[2] + ws[3];
}

// ---- scan phase 2: scan chunk sums (nc <= 1024) ----
__global__ __launch_bounds__(1024) void k_s2(const int* __restrict__ psum,
                                             int* __restrict__ pbase, int nc) {
  __shared__ int sh[1024];
  int t = threadIdx.x;
  int v = (t < nc) ? psum[t] : 0;
  sh[t] = v;
  __syncthreads();
  for (int o = 1; o < 1024; o <<= 1) {
    int u = (t >= o) ? sh[t - o] : 0;
    __syncthreads();
    sh[t] += u;
    __syncthreads();
  }
  if (t < nc) pbase[t] = sh[t] - v;
}

// ---- scan phase 3: element-wise exclusive scan ----
__global__ __launch_bounds__(256) void k_s3(const int* __restrict__ a,
                                            const int* __restrict__ pbase,
                                            int* __restrict__ out, int S) {
  __shared__ int sh[256];
  int t = threadIdx.x;
  int i = blockIdx.x * 256 + t;
  int d = (i < S) ? a[i] : 0;
  sh[t] = d;
  __syncthreads();
  for (int o = 1; o < 256; o <<= 1) {
    int u = (t >= o) ? sh[t - o] : 0;
    __syncthreads();
    sh[t] += u;
    __syncthreads();
  }
  if (i < S) out[i] = pbase[blockIdx.x] + sh[t] - d;
}

// ---- partition: each block writes its own contiguous segments ----
__global__ __launch_bounds__(1024) void k_part2(const int* __restrict__ row,
                                                const int* __restrict__ col,
                                                const int* __restrict__ sbase,
                                                unsigned* __restrict__ tmp,
                                                int nE, int nb) {
  __shared__ int cur[1024];
  for (int i = threadIdx.x; i < nb; i += 1024)
    cur[i] = sbase[i * NBLK + blockIdx.x];
  __syncthreads();
  int chunk = (nE + NBLK - 1) / NBLK;
  int beg = blockIdx.x * chunk, end = min(beg + chunk, nE);
  for (int e = beg + threadIdx.x; e < end; e += 1024) {
    int c = col[e];
    int pos = atomicAdd(&cur[c >> 6], 1);
    tmp[pos] = ((unsigned)(c & 63) << 16) | (unsigned)row[e];
  }
}

// ---- per-bucket counting sort -> ebuf + offs + dinv ----
__global__ __launch_bounds__(256) void k_bsort(const unsigned* __restrict__ tmp,
                                               const int* __restrict__ sbase,
                                               int* __restrict__ ebuf,
                                               int* __restrict__ offs,
                                               float* __restrict__ dinv, int n,
                                               int nE, int nb) {
  __shared__ int bins[64], cur[64];
  int b = blockIdx.x;
  int beg = sbase[b * NBLK];
  int end = (b == nb - 1) ? nE : sbase[(b + 1) * NBLK];
  int t = threadIdx.x;
  if (t == 0 && b == nb - 1) offs[n] = nE;
  if (t < 64) bins[t] = 0;
  __syncthreads();
  for (int i = beg + t; i < end; i += 256) atomicAdd(&bins[tmp[i] >> 16], 1);
  __syncthreads();
  if (t < 64) {  // wave 0: exclusive scan of 64 bins via shfl
    int v = bins[t];
    int s = v;
#pragma unroll
    for (int o = 1; o < 64; o <<= 1) {
      int u = __shfl_up(s, o);
      if (t >= o) s += u;
    }
    int off = beg + s - v;
    cur[t] = off;
    int node = b * 64 + t;
    if (node < n) {
      offs[node] = off;
      dinv[node] = rsqrtf((float)(v + 1));  // +1 self loop
    }
  }
  __syncthreads();
  for (int i = beg + t; i < end; i += 256) {
    unsigned p = tmp[i];
    int pos = atomicAdd(&cur[p >> 16], 1);
    ebuf[pos] = (int)(p & 0xffffu);
  }
}

// ---------------- pack both W matrices into bf16 B-fragments ----------------
// frag(nt, ks): lane l holds B[k = ks*32 + (l>>4)*8 + j][n = nt*16 + (l&15)]
__device__ inline void packOne(const float* __restrict__ W,
                               unsigned short* __restrict__ Wp, int idx, int KS,
                               int OUT) {
  int lane = idx & 63;
  int t = idx >> 6;
  int ks = t % KS;
  int nt = t / KS;
  int n = nt * 16 + (lane & 15);
  int k0 = ks * 32 + (lane >> 4) * 8;
  unsigned short v[8];
#pragma unroll
  for (int j = 0; j < 8; j++) v[j] = f2bf(W[(size_t)(k0 + j) * OUT + n]);
  *reinterpret_cast<short8*>(Wp + (size_t)idx * 8) =
      *reinterpret_cast<short8*>(v);
}

__global__ __launch_bounds__(256) void k_packW_both(
    const float* __restrict__ W1, const float* __restrict__ W2,
    unsigned short* __restrict__ W1p, unsigned short* __restrict__ W2p) {
  int idx = blockIdx.x * 256 + threadIdx.x;
  if (idx < 4096) packOne(W1, W1p, idx, 4, 256);
  else packOne(W2, W2p, idx - 4096, 8, 128);
}

// ---------------- xs = bf16(dinv[row] * X) ----------------
__global__ __launch_bounds__(256) void k_cvt(const float* __restrict__ X,
                                             const float* __restrict__ dinv,
                                             unsigned short* __restrict__ xs,
                                             int n) {
  int i4 = blockIdx.x * 256 + threadIdx.x;  // float4 index, 32 per row
  if (i4 >= n * 32) return;
  int row = i4 >> 5;
  float4 v = reinterpret_cast<const float4*>(X)[i4];
  float d = dinv[row];
  unsigned short o[4] = {f2bf(v.x * d), f2bf(v.y * d), f2bf(v.z * d),
                         f2bf(v.w * d)};
  reinterpret_cast<ushort4*>(xs)[i4] = *reinterpret_cast<ushort4*>(o);
}

// ---------------- bf16 gather-aggregate over 128-wide rows ----------------
// OUT[i] = bf16( dinv[i]*(G[i] + sum_{src in-edges} G[src]) )
__global__ __launch_bounds__(256) void k_agg_bf(
    const unsigned int* __restrict__ G, const int* __restrict__ offs,
    const int* __restrict__ ebuf, const float* __restrict__ dinv,
    unsigned int* __restrict__ OUTP, int n) {
  int node = blockIdx.x * 4 + (threadIdx.x >> 6);
  if (node >= n) return;
  int lane = threadIdx.x & 63;
  int beg = offs[node], end = offs[node + 1];
  unsigned su = G[(size_t)node * 64 + lane];
  float a0 = bflo(su), a1 = bfhi(su);
  int e = beg;
  for (; e + 4 <= end; e += 4) {
    int s0 = ebuf[e], s1 = ebuf[e + 1], s2 = ebuf[e + 2], s3 = ebuf[e + 3];
    unsigned v0 = G[(size_t)s0 * 64 + lane];
    unsigned v1 = G[(size_t)s1 * 64 + lane];
    unsigned v2 = G[(size_t)s2 * 64 + lane];
    unsigned v3 = G[(size_t)s3 * 64 + lane];
    a0 += bflo(v0) + bflo(v1) + bflo(v2) + bflo(v3);
    a1 += bfhi(v0) + bfhi(v1) + bfhi(v2) + bfhi(v3);
  }
  for (; e < end; e++) {
    unsigned v = G[(size_t)ebuf[e] * 64 + lane];
    a0 += bflo(v);
    a1 += bfhi(v);
  }
  float d = dinv[node];
  OUTP[(size_t)node * 64 + lane] =
      (unsigned)f2bf(a0 * d) | ((unsigned)f2bf(a1 * d) << 16);
}

// ---------------- agg2 fused with head projection ----------------
// hf_row = dinv*(G[i] + sum_in G[src]) + b2   (kept in registers, fp32)
// q[i] = { hf_row . Wl[0:128], hf_row . Wl[128:256] }
__global__ __launch_bounds__(256) void k_agg_q(
    const unsigned int* __restrict__ G, const int* __restrict__ offs,
    const int* __restrict__ ebuf, const float* __restrict__ dinv,
    const float* __restrict__ b2, const float* __restrict__ Wl,
    float2* __restrict__ q, int n) {
  int node = blockIdx.x * 4 + (threadIdx.x >> 6);
  if (node >= n) return;
  int lane = threadIdx.x & 63;
  int beg = offs[node], end = offs[node + 1];
  unsigned su = G[(size_t)node * 64 + lane];
  float a0 = bflo(su), a1 = bfhi(su);
  int e = beg;
  for (; e + 4 <= end; e += 4) {
    int s0 = ebuf[e], s1 = ebuf[e + 1], s2 = ebuf[e + 2], s3 = ebuf[e + 3];
    unsigned v0 = G[(size_t)s0 * 64 + lane];
    unsigned v1 = G[(size_t)s1 * 64 + lane];
    unsigned v2 = G[(size_t)s2 * 64 + lane];
    unsigned v3 = G[(size_t)s3 * 64 + lane];
    a0 += bflo(v0) + bflo(v1) + bflo(v2) + bflo(v3);
    a1 += bfhi(v0) + bfhi(v1) + bfhi(v2) + bfhi(v3);
  }
  for (; e < end; e++) {
    unsigned v = G[(size_t)ebuf[e] * 64 + lane];
    a0 += bflo(v);
    a1 += bfhi(v);
  }
  float d = dinv[node];
  a0 = a0 * d + b2[2 * lane];
  a1 = a1 * d + b2[2 * lane + 1];
  float q1 = a0 * Wl[2 * lane] + a1 * Wl[2 * lane + 1];
  float q2 = a0 * Wl[128 + 2 * lane] + a1 * Wl[129 + 2 * lane];
#pragma unroll
  for (int o = 32; o; o >>= 1) {
    q1 += __shfl_down(q1, o);
    q2 += __shfl_down(q2, o);
  }
  if (lane == 0) q[node] = make_float2(q1, q2);
}

// ---------------- fused double GEMM, 32-row tiles ----------------
// per block (4 waves): rows rt0*16 .. rt0*16+31.
//   phase A: h1 = relu(z@W1 + b1)  [32x256] -> LDS (row stride 264 shorts)
//   phase B: g2 = (h1@W2) * dinv    [32x128] -> global
// callers allocate 16 rows of slack in z/g2/dinv so the odd tail needs no guard.
__global__ __launch_bounds__(256) void k_mfma_fused(
    const unsigned short* __restrict__ A, const unsigned short* __restrict__ B1p,
    const unsigned short* __restrict__ B2p, const float* __restrict__ b1,
    const float* __restrict__ dinv, unsigned short* __restrict__ G2) {
  __shared__ unsigned short sh1[32 * 264];  // +8 pad: 2-way LDS conflicts only
  int rt0 = blockIdx.x * 2;
  int wave = threadIdx.x >> 6;
  int lane = threadIdx.x & 63;
  int quad = lane >> 4;
  int mrow0 = rt0 * 16 + (lane & 15);

  // ---- phase A: cols wave*64 .. wave*64+63 of h1, two 16-row tiles ----
  f32x4 acc[2][4] = {};
  const short8* Ap0 =
      reinterpret_cast<const short8*>(A + (size_t)mrow0 * NFEAT + quad * 8);
  const short8* Ap1 = reinterpret_cast<const short8*>(
      A + (size_t)(mrow0 + 16) * NFEAT + quad * 8);
#pragma unroll
  for (int ks = 0; ks < 4; ks++) {
    short8 a0 = Ap0[ks * 4];
    short8 a1 = Ap1[ks * 4];
#pragma unroll
    for (int ct = 0; ct < 4; ct++) {
      int nt = wave * 4 + ct;
      short8 b = *reinterpret_cast<const short8*>(
          B1p + ((size_t)(nt * 4 + ks) * 64 + lane) * 8);
      acc[0][ct] = __builtin_amdgcn_mfma_f32_16x16x32_bf16(a0, b, acc[0][ct], 0, 0, 0);
      acc[1][ct] = __builtin_amdgcn_mfma_f32_16x16x32_bf16(a1, b, acc[1][ct], 0, 0, 0);
    }
  }
#pragma unroll
  for (int ct = 0; ct < 4; ct++) {
    int c = (wave * 4 + ct) * 16 + (lane & 15);
    float bv = b1[c];
#pragma unroll
    for (int rg = 0; rg < 2; rg++)
#pragma unroll
      for (int i = 0; i < 4; i++) {
        float v = fmaxf(acc[rg][ct][i] + bv, 0.f);
        sh1[(rg * 16 + quad * 4 + i) * 264 + c] = f2bf(v);
      }
  }
  __syncthreads();

  // ---- phase B: cols wave*32 .. wave*32+31 of g2, K=256 from LDS ----
  f32x4 acc2[2][2] = {};
  const unsigned short* a2_0 = sh1 + (size_t)(lane & 15) * 264 + quad * 8;
  const unsigned short* a2_1 = sh1 + (size_t)(16 + (lane & 15)) * 264 + quad * 8;
#pragma unroll
  for (int ks = 0; ks < 8; ks++) {
    short8 a0 = *reinterpret_cast<const short8*>(a2_0 + ks * 32);
    short8 a1 = *reinterpret_cast<const short8*>(a2_1 + ks * 32);
#pragma unroll
    for (int ct = 0; ct < 2; ct++) {
      int nt = wave * 2 + ct;
      short8 b = *reinterpret_cast<const short8*>(
          B2p + ((size_t)(nt * 8 + ks) * 64 + lane) * 8);
      acc2[0][ct] = __builtin_amdgcn_mfma_f32_16x16x32_bf16(a0, b, acc2[0][ct], 0, 0, 0);
      acc2[1][ct] = __builtin_amdgcn_mfma_f32_16x16x32_bf16(a1, b, acc2[1][ct], 0, 0, 0);
    }
  }
#pragma unroll
  for (int rg = 0; rg < 2; rg++) {
    int r0 = (rt0 + rg) * 16 + quad * 4;
    float dv[4];
#pragma unroll
    for (int i = 0; i < 4; i++) dv[i] = dinv[r0 + i];
#pragma unroll
    for (int ct = 0; ct < 2; ct++) {
      int c = (wave * 2 + ct) * 16 + (lane & 15);
#pragma unroll
      for (int i = 0; i < 4; i++)
        G2[(size_t)(r0 + i) * NFEAT + c] = f2bf(acc2[rg][ct][i] * dv[i]);
    }
  }
}

// ---------------- link head: sigmoid(q1[m0] + q2[m1] + bl) ----------------
__global__ __launch_bounds__(256) void k_head2(const float2* __restrict__ q,
                                               const int* __restrict__ mask,
                                               const float* __restrict__ bl,
                                               float* __restrict__ out, int P) {
  int p = blockIdx.x * 256 + threadIdx.x;
  if (p >= P) return;
  int m0 = mask[2 * p], m1 = mask[2 * p + 1];
  float s = q[m0].x + q[m1].y + bl[0];
  out[p] = 1.0f / (1.0f + expf(-s));
}

extern "C" void kernel_launch(void* const* d_in, const int* in_sizes, int n_in,
                              void* d_out, int out_size, void* d_ws,
                              size_t ws_size, hipStream_t stream) {
  const int* edge = (const int*)d_in[0];
  const float* feat = (const float*)d_in[1];
  const int* mask = (const int*)d_in[2];
  const float* W1 = (const float*)d_in[3];
  const float* b1 = (const float*)d_in[4];
  const float* W2 = (const float*)d_in[5];
  const float* b2 = (const float*)d_in[6];
  const float* Wl = (const float*)d_in[7];
  const float* bl = (const float*)d_in[8];
  float* out = (float*)d_out;

  const int E = in_sizes[0] / 2;
  const int N = in_sizes[1] / NFEAT;  // must be <= 65536 (16-bit packing)
  const int P = in_sizes[2] / 2;
  const int* rowp = edge;
  const int* colp = edge + E;
  const int nrt = N / 16;             // 3125 for N=50000
  const int nb = (N + 63) / 64;       // 782 buckets (<= 1024 required)
  const int S = nb * NBLK;            // 100096 hist entries
  const int nS = (S + 255) / 256;     // 392 scan chunks (<= 1024 required)

  auto aln = [](size_t x) { return (x + 255) & ~(size_t)255; };
  const size_t rowSlack = (size_t)16 * NFEAT * 2;  // 16-row tail slack
  char* w = (char*)d_ws;
  int* hist2d = (int*)w;           w += aln((size_t)S * 4);
  int* sbase = (int*)w;            w += aln((size_t)S * 4);
  int* psum = (int*)w;             w += aln((size_t)1024 * 4);
  int* pbase = (int*)w;            w += aln((size_t)1024 * 4);
  int* offs = (int*)w;             w += aln((size_t)(N + 1) * 4);
  int* ebuf = (int*)w;             w += aln((size_t)E * 4);
  unsigned* tmp = (unsigned*)w;    w += aln((size_t)E * 4);
  float* dinv = (float*)w;         w += aln((size_t)N * 4 + 1024);
  unsigned short* xs = (unsigned short*)w;  w += aln((size_t)N * NFEAT * 2);
  unsigned short* z = (unsigned short*)w;   w += aln((size_t)N * NFEAT * 2 + rowSlack);
  unsigned short* g2 = (unsigned short*)w;  w += aln((size_t)N * NFEAT * 2 + rowSlack);
  float2* q = (float2*)w;          w += aln((size_t)N * 8);
  unsigned short* W1p = (unsigned short*)w; w += aln((size_t)NFEAT * NHID * 2);
  unsigned short* W2p = (unsigned short*)w; w += aln((size_t)NHID * NFEAT * 2);

  // ---- CSR build: deterministic 2-pass partition ----
  k_hist2<<<NBLK, 1024, 0, stream>>>(colp, hist2d, E, nb);
  k_bsum<<<nS, 256, 0, stream>>>(hist2d, psum, S);
  k_s2<<<1, 1024, 0, stream>>>(psum, pbase, nS);
  k_s3<<<nS, 256, 0, stream>>>(hist2d, pbase, sbase, S);
  k_part2<<<NBLK, 1024, 0, stream>>>(rowp, colp, sbase, tmp, E, nb);
  k_bsort<<<nb, 256, 0, stream>>>(tmp, sbase, ebuf, offs, dinv, N, E, nb);
  k_packW_both<<<32, 256, 0, stream>>>(W1, W2, W1p, W2p);

  // xs = bf16(dinv * X)
  k_cvt<<<(N * 32 + 255) / 256, 256, 0, stream>>>(feat, dinv, xs, N);
  // z = dinv .* (sum_in xs + xs_self)            [= A_norm @ X, bf16]
  k_agg_bf<<<(N + 3) / 4, 256, 0, stream>>>((const unsigned*)xs, offs, ebuf,
                                            dinv, (unsigned*)z, N);
  // g2 = (relu(z@W1+b1) @ W2) .* dinv[row]   (h1 tile stays in LDS)
  k_mfma_fused<<<(nrt + 1) / 2, 256, 0, stream>>>(z, W1p, W2p, b1, dinv, g2);
  // q[i] = {hf_i . Wl_lo, hf_i . Wl_hi},  hf_i = dinv*(sum_in g2 + g2_self)+b2
  k_agg_q<<<(N + 3) / 4, 256, 0, stream>>>((const unsigned*)g2, offs, ebuf,
                                           dinv, b2, Wl, q, N);
  // head: out = sigmoid(q1[m0] + q2[m1] + bl)
  k_head2<<<(P + 255) / 256, 256, 0, stream>>>(q, mask, bl, out, P);
}